// Round 6
// baseline (121.778 us; speedup 1.0000x reference)
//
#include <hip/hip_runtime.h>
#include <hip/hip_bf16.h>
#include <stdint.h>
#include <stddef.h>

// ---------------------------------------------------------------------------
// InteractionPredictionHead: edge MLP.
// feats@W1 = P[src] + Q[dst] + attr@W1c + b1  (P,Q per-node, 50k not 300k).
// R6: fused does FULL-DEPTH gather prefetch: the lane's entire P/Q slice
//   (16 x bf16x8 = 64 VGPR) is loaded in one burst in the prologue; the
//   K=256 layer-2 loop has ZERO global loads (pure ds_read+VALU+MFMA).
//   R5 was stalling every step: prefetch distance 2 (~300cyc) < L3 gather
//   latency (~600-900cyc).
// Layers 2-4: mfma_f32_16x16x32_bf16, 16 edges/wave, W2/W3/W4 in LDS
//   (W3/W4 + h-slots aliased into W2's region after the L2 loop).
// gemm1: 32x32x16, out-half blocks, W1 slice register-stationary.
// ---------------------------------------------------------------------------

#define NN 50000
#define NE 300000
#define KG(kq,g2) ((kq)*2+(g2))

using bf16x8 = __attribute__((ext_vector_type(8))) short;
using f32x16 = __attribute__((ext_vector_type(16))) float;
using f32x4  = __attribute__((ext_vector_type(4))) float;
using f32x2  = __attribute__((ext_vector_type(2))) float;
using u32x4  = __attribute__((ext_vector_type(4))) unsigned int;
using u32x2  = __attribute__((ext_vector_type(2))) unsigned int;

// ---- ws layout (bytes, 16B aligned) ----
#define OFF_PQ   0ULL
#define SZ_PQ    (50000ULL*512ULL*2ULL)          // PQ bf16 [n][512]
#define OFF_W1   (OFF_PQ + SZ_PQ)                // W1 img (32-style) [kg32][512][8]
#define SZ_W1    (512ULL*256ULL*2ULL)
#define OFF_W1C  (OFF_W1 + SZ_W1)                // W1c f32 [3][256]
#define SZ_W1C   (3ULL*256ULL*4ULL)
#define OFF_W2   (OFF_W1C + SZ_W1C)              // W2 img (16-style) [sg32][128][8]
#define SZ_W2    (128ULL*256ULL*2ULL)
#define OFF_W3   (OFF_W2 + SZ_W2)                // W3 img (16-style) [sg16][64][8]
#define SZ_W3    (64ULL*128ULL*2ULL)
#define OFF_W4   (OFF_W3 + SZ_W3)                // W4 img (16-style) [sg8][16][8]
#define SZ_W4    (16ULL*64ULL*2ULL)
#define OFF_FLAG (OFF_W4 + SZ_W4)
#define WS_NEED  (OFF_FLAG + 16ULL)

__device__ __forceinline__ unsigned short f2bf(float x){
  unsigned u = __float_as_uint(x);
  unsigned r = 0x7FFFu + ((u >> 16) & 1u);
  return (unsigned short)((u + r) >> 16);
}
__device__ __forceinline__ unsigned cvtpk(float lo, float hi){
  unsigned r;
  asm("v_cvt_pk_bf16_f32 %0, %1, %2" : "=v"(r) : "v"(lo), "v"(hi));
  return r;
}
__device__ __forceinline__ f32x2 unpk(unsigned w){
  f32x2 r;
  r[0] = __uint_as_float(w << 16);
  r[1] = __uint_as_float(w & 0xFFFF0000u);
  return r;
}
__device__ __forceinline__ f32x16 mfma32(bf16x8 a, bf16x8 b, f32x16 c){
  return __builtin_amdgcn_mfma_f32_32x32x16_bf16(a, b, c, 0, 0, 0);
}
__device__ __forceinline__ f32x4 mfma16(bf16x8 a, bf16x8 b, f32x4 c){
  return __builtin_amdgcn_mfma_f32_16x16x32_bf16(a, b, c, 0, 0, 0);
}
__device__ __forceinline__ f32x16 zero16(){
  f32x16 v;
#pragma unroll
  for (int i = 0; i < 16; ++i) v[i] = 0.f;
  return v;
}

// ---------------------------------------------------------------------------
// prep_pack: weight images + int64 flag.
// threads = 131072 (W1) + 32768 (W2) + 8192 (W3) + 1024 (W4) = 173056 = 676*256
// ---------------------------------------------------------------------------
__global__ void prep_pack(const float* __restrict__ W1, const float* __restrict__ W2,
                          const float* __restrict__ W3, const float* __restrict__ W4,
                          const int* __restrict__ ei32, char* __restrict__ ws)
{
  int i = blockIdx.x * 256 + threadIdx.x;
  unsigned short* w1i = (unsigned short*)(ws + OFF_W1);
  unsigned short* w2i = (unsigned short*)(ws + OFF_W2);
  unsigned short* w3i = (unsigned short*)(ws + OFF_W3);
  unsigned short* w4i = (unsigned short*)(ws + OFF_W4);

  if (i < 131072){
    // 32-style: idx = (kg*512 + out)*8 + j ; k = (kg>>1)*16 + (kg&1)*8 + j
    int j = i & 7, out = (i >> 3) & 511, kg = i >> 12;
    int k = (kg >> 1)*16 + (kg & 1)*8 + j;
    float v = (out < 256) ? W1[(size_t)k*256 + out]
                          : W1[(size_t)(256 + k)*256 + (out - 256)];
    w1i[i] = f2bf(v);
  } else if (i < 131072 + 32768){
    // 16-style: idx = (sg*128 + out)*8 + j ; k = (sg>>2)*32 + (sg&3)*8 + j
    int i2 = i - 131072;
    int j = i2 & 7, out = (i2 >> 3) & 127, sg = i2 >> 10;
    int k = (sg >> 2)*32 + (sg & 3)*8 + j;
    w2i[i2] = f2bf(W2[(size_t)k*128 + out]);
  } else if (i < 131072 + 32768 + 8192){
    int i3 = i - 131072 - 32768;
    int j = i3 & 7, out = (i3 >> 3) & 63, sg = i3 >> 9;
    int k = (sg >> 2)*32 + (sg & 3)*8 + j;
    w3i[i3] = f2bf(W3[(size_t)k*64 + out]);
  } else if (i < 131072 + 32768 + 8192 + 1024){
    int i4 = i - 131072 - 32768 - 8192;
    int j = i4 & 7, out = (i4 >> 3) & 15, sg = i4 >> 7;
    int k = (sg >> 2)*32 + (sg & 3)*8 + j;
    w4i[i4] = (out < 3) ? f2bf(W4[(size_t)k*3 + out]) : (unsigned short)0;
  }
  if (i < 768){
    float* w1c = (float*)(ws + OFF_W1C);
    w1c[i] = W1[(size_t)(512 + i/256)*256 + (i & 255)];
  }
  if (i == 0){
    int f = 1;
    for (int t = 1; t < 64; t += 2) if (ei32[t] != 0) { f = 0; break; }
    *(int*)(ws + OFF_FLAG) = f;
  }
}

// ---------------------------------------------------------------------------
// gemm1: PQ = emb @ W1ab (+b1). Out-half blocks: grid = 782 nodegrps x 2.
// 512 thr, 8 waves x 32 outs (reg-stationary aw[16] = 64 VGPR), 64 nodes.
// ---------------------------------------------------------------------------
__global__ __launch_bounds__(512, 4) void gemm1(const float* __restrict__ emb,
                                                const float* __restrict__ b1,
                                                char* __restrict__ ws)
{
  __shared__ __align__(16) unsigned short embL[32*64*8];  // 32KB [kg][node][8]

  const int tid = threadIdx.x;
  const int wv = tid >> 6, l = tid & 63, ln = l & 31, g2 = l >> 5;
  const int bid = blockIdx.x;
  const int nb = (bid >> 1) * 64;
  const int oh = bid & 1;
  const int ob = oh*256 + wv*32;
  const unsigned short* w1L = (const unsigned short*)(ws + OFF_W1);
  unsigned short* PQ = (unsigned short*)(ws + OFF_PQ);

  // weight preload: 16 frags (64 VGPR), contiguous 16B/lane
  bf16x8 aw[16];
#pragma unroll
  for (int kq = 0; kq < 16; ++kq)
    aw[kq] = *(const bf16x8*)(w1L + ((size_t)KG(kq,g2)*512 + ob + ln)*8);

  // stage emb tile -> LDS bf16 k-major
#pragma unroll
  for (int it = 0; it < 8; ++it){
    int u = it*512 + tid;                      // 0..4095
    int kg = u >> 7, node = (u >> 1) & 63, half = u & 1;
    int n = nb + node; if (n >= NN) n = NN - 1;
    int k = (kg >> 1)*16 + (kg & 1)*8 + half*4;
    f32x4 e = *(const f32x4*)(emb + (size_t)n*256 + k);
    u32x2 w; w[0] = cvtpk(e[0], e[1]); w[1] = cvtpk(e[2], e[3]);
    *(u32x2*)(embL + (size_t)kg*512 + node*8 + half*4) = w;
  }
  __syncthreads();

  f32x16 acc0 = zero16(), acc1 = zero16();
#pragma unroll
  for (int kq = 0; kq < 16; ++kq){
    bf16x8 b0  = *(const bf16x8*)(embL + ((size_t)KG(kq,g2)*64 +      ln)*8);
    bf16x8 b1v = *(const bf16x8*)(embL + ((size_t)KG(kq,g2)*64 + 32 + ln)*8);
    acc0 = mfma32(aw[kq], b0,  acc0);
    acc1 = mfma32(aw[kq], b1v, acc1);
  }

#pragma unroll
  for (int bg = 0; bg < 2; ++bg){
    int n = nb + bg*32 + ln;
    if (n < NN){
#pragma unroll
      for (int rr = 0; rr < 4; ++rr){
        int o = ob + rr*8 + g2*4;
        f32x4 bv = {0.f,0.f,0.f,0.f};
        if (oh == 0) bv = *(const f32x4*)(b1 + o);
        unsigned d0, d1;
        if (bg == 0){
          d0 = cvtpk(acc0[rr*4+0]+bv[0], acc0[rr*4+1]+bv[1]);
          d1 = cvtpk(acc0[rr*4+2]+bv[2], acc0[rr*4+3]+bv[3]);
        } else {
          d0 = cvtpk(acc1[rr*4+0]+bv[0], acc1[rr*4+1]+bv[1]);
          d1 = cvtpk(acc1[rr*4+2]+bv[2], acc1[rr*4+3]+bv[3]);
        }
        u32x2 st = {d0, d1};
        *(u32x2*)(PQ + (size_t)n*512 + o) = st;
      }
    }
  }
}

// ---------------------------------------------------------------------------
// fused: 512 thr (8 waves), 16 edges/wave, 16x16x32 MFMA.
// LDS: [0,65536) = W2 image -> (after L2) hslots + W3/W4; [65536,68608) = w1c.
// Full-depth gather prefetch: p0..p7/q0..q7 named regs, loaded in prologue.
// ---------------------------------------------------------------------------

#define PAIRX(LO, HI, D) ((D)==0 ? (f32x2){(LO)[0],(LO)[1]} : \
                          (D)==1 ? (f32x2){(LO)[2],(LO)[3]} : \
                          (D)==2 ? (f32x2){(HI)[0],(HI)[1]} : \
                                   (f32x2){(HI)[2],(HI)[3]})

// One K=32 step of layer 2: build h1 B-frag in regs from preloaded PC/QC,
// then 8 MFMA tiles with A-frags from LDS.
#define L2STEP(S, PC, QC)                                                      \
  {                                                                            \
    const int ks_ = (S);                                                       \
    const int kb = ks_*32 + g4*8;                                              \
    f32x4 w0lo = *(const f32x4*)(w1c_lds +   0 + kb);                          \
    f32x4 w0hi = *(const f32x4*)(w1c_lds +   4 + kb);                          \
    f32x4 w1lo = *(const f32x4*)(w1c_lds + 256 + kb);                          \
    f32x4 w1hi = *(const f32x4*)(w1c_lds + 260 + kb);                          \
    f32x4 w2lo = *(const f32x4*)(w1c_lds + 512 + kb);                          \
    f32x4 w2hi = *(const f32x4*)(w1c_lds + 516 + kb);                          \
    u32x4 pu = __builtin_bit_cast(u32x4, PC);                                  \
    u32x4 qu = __builtin_bit_cast(u32x4, QC);                                  \
    f32x2 z2 = {0.f, 0.f};                                                     \
    unsigned bu0, bu1, bu2, bu3;                                               \
    _Pragma("unroll")                                                          \
    for (int d = 0; d < 4; ++d){                                               \
      f32x2 h = unpk(pu[d]) + unpk(qu[d]);                                     \
      h += PAIRX(w0lo, w0hi, d) * at0;                                         \
      h += PAIRX(w1lo, w1hi, d) * at1;                                         \
      h += PAIRX(w2lo, w2hi, d) * at2;                                         \
      h = __builtin_elementwise_max(h, z2);                                    \
      unsigned c = cvtpk(h[0], h[1]);                                          \
      if (d==0) bu0 = c; else if (d==1) bu1 = c; else if (d==2) bu2 = c;       \
      else bu3 = c;                                                            \
    }                                                                          \
    u32x4 buv = {bu0, bu1, bu2, bu3};                                          \
    bf16x8 b = __builtin_bit_cast(bf16x8, buv);                                \
    const char* abase = smem + (size_t)(ks_*4 + g4)*2048 + c16*16;             \
    _Pragma("unroll")                                                          \
    for (int t = 0; t < 8; ++t){                                               \
      bf16x8 af = *(const bf16x8*)(abase + t*256);                             \
      acc2[t] = mfma16(af, b, acc2[t]);                                        \
    }                                                                          \
  }

__global__ __launch_bounds__(512, 4) void fused(const int* __restrict__ eidx,
                                                const float* __restrict__ attr,
                                                const float* __restrict__ b2,
                                                const float* __restrict__ b3,
                                                const float* __restrict__ b4,
                                                const char* __restrict__ ws,
                                                float* __restrict__ out)
{
  __shared__ __align__(16) char smem[68608];
  const int tid = threadIdx.x;
  const int wv = tid >> 6, l = tid & 63, c16 = l & 15, g4 = l >> 4;

  const unsigned short* PQ = (const unsigned short*)(ws + OFF_PQ);
  const float* W1c = (const float*)(ws + OFF_W1C);
  const int flag64 = *(const int*)(ws + OFF_FLAG);
  const float* w1c_lds = (const float*)(smem + 65536);

  const int eb = blockIdx.x * 128 + wv * 16;
  const int e = eb + c16;
  const bool ev = (e < NE);
  const int ec = ev ? e : 0;
  const int si = flag64 ? eidx[2*(size_t)ec]        : eidx[ec];
  const int di = flag64 ? eidx[2*((size_t)NE + ec)] : eidx[NE + ec];

  // ---- full-depth gather prefetch: whole P/Q lane-slice, 16 loads --------
  const unsigned short* Prow = PQ + (size_t)si*512 + g4*8;
  const unsigned short* Qrow = PQ + (size_t)di*512 + 256 + g4*8;
  bf16x8 p0 = *(const bf16x8*)(Prow +   0), p1 = *(const bf16x8*)(Prow +  32);
  bf16x8 p2 = *(const bf16x8*)(Prow +  64), p3 = *(const bf16x8*)(Prow +  96);
  bf16x8 p4 = *(const bf16x8*)(Prow + 128), p5 = *(const bf16x8*)(Prow + 160);
  bf16x8 p6 = *(const bf16x8*)(Prow + 192), p7 = *(const bf16x8*)(Prow + 224);
  bf16x8 q0 = *(const bf16x8*)(Qrow +   0), q1 = *(const bf16x8*)(Qrow +  32);
  bf16x8 q2 = *(const bf16x8*)(Qrow +  64), q3 = *(const bf16x8*)(Qrow +  96);
  bf16x8 q4 = *(const bf16x8*)(Qrow + 128), q5 = *(const bf16x8*)(Qrow + 160);
  bf16x8 q6 = *(const bf16x8*)(Qrow + 192), q7 = *(const bf16x8*)(Qrow + 224);

  const float at0 = ev ? attr[(size_t)ec*3 + 0] : 0.f;
  const float at1 = ev ? attr[(size_t)ec*3 + 1] : 0.f;
  const float at2 = ev ? attr[(size_t)ec*3 + 2] : 0.f;

  // stage W2 (64KB, linear) + w1c (3KB) while gathers are in flight
  {
    const uint4* src = (const uint4*)(ws + OFF_W2);
    uint4* dst = (uint4*)smem;
#pragma unroll
    for (int it = 0; it < 8; ++it) dst[it*512 + tid] = src[it*512 + tid];
    if (tid < 192) ((f32x4*)(smem + 65536))[tid] = ((const f32x4*)W1c)[tid];
  }
  __syncthreads();

  // ---------------- Layer 2: K=256 (8 x 32k-steps), 128 outs ---------------
  f32x4 acc2[8];
#pragma unroll
  for (int t = 0; t < 8; ++t) acc2[t] = (f32x4){0.f,0.f,0.f,0.f};

  L2STEP(0, p0, q0);
  L2STEP(1, p1, q1);
  L2STEP(2, p2, q2);
  L2STEP(3, p3, q3);
  L2STEP(4, p4, q4);
  L2STEP(5, p5, q5);
  L2STEP(6, p6, q6);
  L2STEP(7, p7, q7);

  __syncthreads();   // everyone done reading W2 region

  // stage W3+W4 (contiguous in ws: 16384+2048 = 18432B) into dead W2 space
  {
    const uint4* s3 = (const uint4*)(ws + OFF_W3);
    uint4* d3 = (uint4*)(smem + 36864);
    for (int i = tid; i < 1152; i += 512) d3[i] = s3[i];
  }

  // write h2 -> per-wave hslot [16 edges][136] bf16 (stride 272B)
  unsigned short* hslot = (unsigned short*)(smem + wv*4352);
#pragma unroll
  for (int t = 0; t < 8; ++t){
    f32x4 bv = *(const f32x4*)(b2 + t*16 + g4*4);
    unsigned d0 = cvtpk(acc2[t][0]+bv[0], acc2[t][1]+bv[1]);
    unsigned d1 = cvtpk(acc2[t][2]+bv[2], acc2[t][3]+bv[3]);
    u32x2 st = {d0, d1};
    *(u32x2*)(hslot + (size_t)c16*136 + t*16 + g4*4) = st;
  }
  __syncthreads();   // W3/W4 visible

  // ---------------- Layer 3: K=128 (4 steps), 64 outs ----------------------
  f32x4 acc3[4];
#pragma unroll
  for (int t = 0; t < 4; ++t) acc3[t] = (f32x4){0.f,0.f,0.f,0.f};
  const char* w3b = smem + 36864;
#pragma unroll
  for (int ks = 0; ks < 4; ++ks){
    bf16x8 bb = *(const bf16x8*)(hslot + (size_t)c16*136 + ks*32 + g4*8);
    const char* ab = w3b + (size_t)(ks*4 + g4)*1024 + c16*16;
#pragma unroll
    for (int t = 0; t < 4; ++t){
      bf16x8 af = *(const bf16x8*)(ab + t*256);
      acc3[t] = mfma16(af, bb, acc3[t]);
    }
  }

  // h3 -> hslot (relu, +b3); same-wave RAW on LDS is in-order
#pragma unroll
  for (int t = 0; t < 4; ++t){
    f32x4 bv = *(const f32x4*)(b3 + t*16 + g4*4);
    unsigned d0 = cvtpk(fmaxf(acc3[t][0]+bv[0],0.f), fmaxf(acc3[t][1]+bv[1],0.f));
    unsigned d1 = cvtpk(fmaxf(acc3[t][2]+bv[2],0.f), fmaxf(acc3[t][3]+bv[3],0.f));
    u32x2 st = {d0, d1};
    *(u32x2*)(hslot + (size_t)c16*136 + t*16 + g4*4) = st;
  }

  // ---------------- Layer 4: K=64 (2 steps), 3 outs ------------------------
  f32x4 acc4 = {0.f,0.f,0.f,0.f};
  const char* w4b = smem + 53248;
#pragma unroll
  for (int ks = 0; ks < 2; ++ks){
    bf16x8 bb = *(const bf16x8*)(hslot + (size_t)c16*136 + ks*32 + g4*8);
    bf16x8 af = *(const bf16x8*)(w4b + (size_t)(ks*4 + g4)*256 + c16*16);
    acc4 = mfma16(af, bb, acc4);
  }
  if (g4 == 0 && ev){
    out[(size_t)e*3 + 0] = acc4[0] + b4[0];
    out[(size_t)e*3 + 1] = acc4[1] + b4[1];
    out[(size_t)e*3 + 2] = acc4[2] + b4[2];
  }
}

// ---------------------------------------------------------------------------
extern "C" void kernel_launch(void* const* d_in, const int* in_sizes, int n_in,
                              void* d_out, int out_size, void* d_ws, size_t ws_size,
                              hipStream_t stream)
{
  const float* emb  = (const float*)d_in[0];
  const int*   eidx = (const int*)  d_in[1];
  const float* attr = (const float*)d_in[2];
  const float* W1   = (const float*)d_in[3];
  const float* b1   = (const float*)d_in[4];
  const float* W2   = (const float*)d_in[5];
  const float* b2   = (const float*)d_in[6];
  const float* W3   = (const float*)d_in[7];
  const float* b3   = (const float*)d_in[8];
  const float* W4   = (const float*)d_in[9];
  const float* b4   = (const float*)d_in[10];
  char* ws = (char*)d_ws;
  float* out = (float*)d_out;

  if (ws_size < WS_NEED) return;

  prep_pack<<<676, 256, 0, stream>>>(W1, W2, W3, W4, eidx, ws);
  gemm1<<<((NN + 63)/64)*2, 512, 0, stream>>>(emb, b1, ws);
  fused<<<(NE + 127)/128, 512, 0, stream>>>(eidx, attr, b2, b3, b4, ws, out);
}